// Round 14
// baseline (6066.674 us; speedup 1.0000x reference)
//
#include <hip/hip_runtime.h>
#include <hip/hip_bf16.h>

#define Bb   64
#define Tt   512
#define INN  256
#define HH   1024
#define OUTN 512

#define NCOL 32              // output cols per block
#define MG   16              // batch rows per group
#define NGRP (Bb / MG)       // 4 groups
#define NSLOT 64             // wave flags per (group, stage) = 32 blocks x 2 waves

typedef __attribute__((ext_vector_type(8))) short bf16x8;
typedef __attribute__((ext_vector_type(4))) float f32x4;

__device__ __forceinline__ unsigned short f2b(float f) {
  unsigned u = __float_as_uint(f);
  u += 0x7FFFu + ((u >> 16) & 1u);
  return (unsigned short)(u >> 16);
}
__device__ __forceinline__ float b2f(unsigned short u) {
  return __uint_as_float((unsigned)u << 16);
}

__device__ __forceinline__ unsigned long long cohLoadU64(const unsigned long long* p) {
  return __hip_atomic_load(p, __ATOMIC_RELAXED, __HIP_MEMORY_SCOPE_AGENT);
}
__device__ __forceinline__ unsigned short cohLoadU16(const unsigned short* p) {
  return __hip_atomic_load(p, __ATOMIC_RELAXED, __HIP_MEMORY_SCOPE_AGENT);
}
__device__ __forceinline__ void cohStoreU16(unsigned short* p, unsigned short v) {
  __hip_atomic_store(p, v, __ATOMIC_RELAXED, __HIP_MEMORY_SCOPE_AGENT);
}

__device__ __forceinline__ f32x4 splat4(float v) { f32x4 r = {v, v, v, v}; return r; }

union U16 { unsigned long long u[2]; bf16x8 v; };

// Device-coherent (MALL-served) pipelined 16B load, literal byte offset.
// Result valid only after a following counted s_waitcnt vmcnt (VMW).
#define ALOADO(d, p, OFF)                                                     \
  asm volatile("global_load_dwordx4 %0, %1, off offset:" #OFF " sc0 sc1"      \
               : "=v"(d) : "v"(p))
#define VMW(N)                                                                \
  do {                                                                        \
    asm volatile("s_waitcnt vmcnt(" #N ")" ::: "memory");                     \
    __builtin_amdgcn_sched_barrier(0);                                        \
  } while (0)

// fp32 -> bf16 (RNE), vectorized x4
__global__ void cvt4(const float* __restrict__ in, unsigned short* __restrict__ out, int n4) {
  int i = blockIdx.x * blockDim.x + threadIdx.x;
  if (i >= n4) return;
  float4 v = ((const float4*)in)[i];
  ushort4 o;
  o.x = f2b(v.x); o.y = f2b(v.y); o.z = f2b(v.z); o.w = f2b(v.w);
  ((ushort4*)out)[i] = o;
}

__global__ void addv(const float* __restrict__ a, const float* __restrict__ b,
                     float* __restrict__ o, int n) {
  int i = blockIdx.x * blockDim.x + threadIdx.x;
  if (i < n) o[i] = a[i] + b[i];
}

__global__ void zerok(unsigned int* __restrict__ p, int n) {
  int i = blockIdx.x * blockDim.x + threadIdx.x;
  if (i < n) p[i] = 0u;
}

// Poll 64 DENSE u16 flags (128 B = ONE MALL line per poll; 16x less fabric
// traffic than the 32B-strided u32 version). Lane l watches slot l.
__device__ __forceinline__ void waitflags(const unsigned short* gf, int l, unsigned need) {
#pragma clang loop unroll(disable)
  for (int guard = 0; guard < 4000000; ++guard) {
    unsigned f = cohLoadU16(gf + l);
    if (__all((int)(f >= need))) return;
    __builtin_amdgcn_s_sleep(1);
  }
}
// Poll a single u16 flag slot (wave-uniform address).
__device__ __forceinline__ void waitflag1(const unsigned short* slot, unsigned need) {
#pragma clang loop unroll(disable)
  for (int guard = 0; guard < 4000000; ++guard) {
    if (cohLoadU16(slot) >= need) return;
    __builtin_amdgcn_s_sleep(1);
  }
}

// One K=1024 GEMM phase for this lane's 16x16 tile.
// A: 32 coherent b128 loads, ALL issued up-front (full-depth pipelining),
// drained with counted vmcnt 24/16/8/0.
// W (B-operand): 32 bf16x8 resident in AGPRs (laundered "+a" at entry each
// call so values stay in AGPRs and per-use copies can't be LICM-hoisted).
#define ISSUE8(V, O0, O1, O2, O3, O4, O5, O6, O7)                             \
  ALOADO(V##0, Ap, O0); ALOADO(V##1, Ap, O1); ALOADO(V##2, Ap, O2);           \
  ALOADO(V##3, Ap, O3); ALOADO(V##4, Ap, O4); ALOADO(V##5, Ap, O5);           \
  ALOADO(V##6, Ap, O6); ALOADO(V##7, Ap, O7);
#define COMP8(V, WI)                                                          \
  acc  = __builtin_amdgcn_mfma_f32_16x16x32_bf16(V##0, w[(WI)+0], acc,  0,0,0);\
  acc2 = __builtin_amdgcn_mfma_f32_16x16x32_bf16(V##1, w[(WI)+1], acc2, 0,0,0);\
  acc  = __builtin_amdgcn_mfma_f32_16x16x32_bf16(V##2, w[(WI)+2], acc,  0,0,0);\
  acc2 = __builtin_amdgcn_mfma_f32_16x16x32_bf16(V##3, w[(WI)+3], acc2, 0,0,0);\
  acc  = __builtin_amdgcn_mfma_f32_16x16x32_bf16(V##4, w[(WI)+4], acc,  0,0,0);\
  acc2 = __builtin_amdgcn_mfma_f32_16x16x32_bf16(V##5, w[(WI)+5], acc2, 0,0,0);\
  acc  = __builtin_amdgcn_mfma_f32_16x16x32_bf16(V##6, w[(WI)+6], acc,  0,0,0);\
  acc2 = __builtin_amdgcn_mfma_f32_16x16x32_bf16(V##7, w[(WI)+7], acc2, 0,0,0);

__device__ __forceinline__ f32x4 kphase(const short* Ap, bf16x8* w, f32x4 acc) {
#pragma unroll
  for (int c = 0; c < 32; ++c) asm volatile("" : "+a"(w[c]));   // pin in AGPRs
  f32x4 acc2 = {0, 0, 0, 0};
  bf16x8 A_0, A_1, A_2, A_3, A_4, A_5, A_6, A_7;
  bf16x8 B_0, B_1, B_2, B_3, B_4, B_5, B_6, B_7;
  bf16x8 C_0, C_1, C_2, C_3, C_4, C_5, C_6, C_7;
  bf16x8 D_0, D_1, D_2, D_3, D_4, D_5, D_6, D_7;
  ISSUE8(A_,    0,   64,  128,  192,  256,  320,  384,  448)
  ISSUE8(B_,  512,  576,  640,  704,  768,  832,  896,  960)
  ISSUE8(C_, 1024, 1088, 1152, 1216, 1280, 1344, 1408, 1472)
  ISSUE8(D_, 1536, 1600, 1664, 1728, 1792, 1856, 1920, 1984)
  VMW(24); COMP8(A_,  0)
  VMW(16); COMP8(B_,  8)
  VMW(8);  COMP8(C_, 16)
  VMW(0);  COMP8(D_, 24)
  return acc + acc2;
}

// 3-stage pipelined persistent RNN (R11 structure — proven 3.35 ms), 384
// blocks (stage = bid%3), 128 thr (2 waves), NO LDS; W in AGPRs (128/wave).
// Flags: dense u16, one 128B line per (group,stage) domain.
//  stage 0 (L0):  h1_t = tanh(Wh0 h1_{t-1} + Wx0 x_t + b0)      -> P0[t], gf0
//  stage 1 (XP1): xp1_t = Wx1 h1_t + b1                         -> P1[t], gfx
//  stage 2 (WH1): h2_t = tanh(Wh1 h2_{t-1} + xp1_t) (in-place)  -> P1[t], gf1
__global__ __launch_bounds__(128) void rnn3(
    const __hip_bfloat16* __restrict__ xs,                        // [B][T][IN]
    const __hip_bfloat16* __restrict__ Wx0, const __hip_bfloat16* __restrict__ Wh0,
    const __hip_bfloat16* __restrict__ Wx1, const __hip_bfloat16* __restrict__ Wh1,
    const float* __restrict__ b0s, const float* __restrict__ b1s,
    __hip_bfloat16* __restrict__ P0, __hip_bfloat16* __restrict__ P1,
    unsigned short* flags)
{
  const int tid = threadIdx.x;
  const int l   = tid & 63;
  const int wv  = tid >> 6;
  const int bid = blockIdx.x;
  const int stage = bid % 3;
  const int idx = bid / 3;          // 0..127
  const int j   = idx & 31;
  const int g   = idx >> 5;
  const int n0  = j * NCOL;
  const int rowA = g * MG;
  const int fr = l & 15;
  const int lh = l >> 4;
  const int rb = lh << 2;
  const int ccol = n0 + wv * 16 + fr;

  unsigned short* gf0 = flags + (0 * NGRP + g) * NSLOT;
  unsigned short* gfx = flags + (1 * NGRP + g) * NSLOT;
  unsigned short* gf1 = flags + (2 * NGRP + g) * NSLOT;
  const int wslot = j * 2 + wv;
  const long laneA = (long)(rowA + fr) * HH + (lh << 3);
  unsigned short* P0u = (unsigned short*)P0;
  unsigned short* P1u = (unsigned short*)P1;

  // This wave's 16-col W slice -> AGPRs (32 x bf16x8 = 128 AGPRs).
  const short* Wg = (const short*)(stage == 0 ? Wh0 : (stage == 1 ? Wx1 : Wh1));
  const short* Wgrow = Wg + (long)ccol * HH + (lh << 3);
  bf16x8 w[32];
#pragma unroll
  for (int c = 0; c < 32; ++c) w[c] = *(const bf16x8*)(Wgrow + (c << 5));
#pragma unroll
  for (int c = 0; c < 32; ++c) asm volatile("" : "+a"(w[c]));

  if (stage == 0) {
    const float bias = b0s[ccol];
    const short* xrow = (const short*)xs + (long)(rowA + fr) * (Tt * INN) + (lh << 3);
    const short* Wx0row = (const short*)Wx0 + (long)ccol * INN + (lh << 3);
    bf16x8 wx[8];
#pragma unroll
    for (int c = 0; c < 8; ++c) wx[c] = *(const bf16x8*)(Wx0row + (c << 5));
#pragma unroll
    for (int c = 0; c < 8; ++c) asm volatile("" : "+a"(wx[c]));
    f32x4 acc = splat4(bias);
#pragma unroll
    for (int c = 0; c < 8; ++c) {     // xp0 for t=0
      bf16x8 a = *(const bf16x8*)(xrow + (c << 5));
      acc = __builtin_amdgcn_mfma_f32_16x16x32_bf16(a, wx[c], acc, 0, 0, 0);
    }
    for (int t = 0; t < Tt; ++t) {
      if (t > 0) {
        waitflags(gf0, l, (unsigned)t);
        acc = kphase((const short*)P0 + (long)(t - 1) * (Bb * HH) + laneA, w, acc);
      }
      const long cb = ((long)t * Bb + rowA + rb) * HH + ccol;
#pragma unroll
      for (int r = 0; r < 4; ++r)
        cohStoreU16(P0u + cb + (long)r * HH, f2b(tanhf(acc[r])));
      asm volatile("s_waitcnt vmcnt(0)" ::: "memory");
      if (l == 0) cohStoreU16(gf0 + wslot, (unsigned short)(t + 1));
      if (t + 1 < Tt) {               // xp0 for t+1, in the straggler window
        acc = splat4(bias);
        const short* xr = xrow + (t + 1) * INN;
#pragma unroll
        for (int c = 0; c < 8; ++c) {
          bf16x8 a = *(const bf16x8*)(xr + (c << 5));
          acc = __builtin_amdgcn_mfma_f32_16x16x32_bf16(a, wx[c], acc, 0, 0, 0);
        }
      }
    }
  } else if (stage == 1) {
    const float bias = b1s[ccol];
    for (int t = 0; t < Tt; ++t) {
      waitflags(gf0, l, (unsigned)(t + 1));
      f32x4 acc = kphase((const short*)P0 + (long)t * (Bb * HH) + laneA, w,
                         splat4(bias));
      const long cb = ((long)t * Bb + rowA + rb) * HH + ccol;
#pragma unroll
      for (int r = 0; r < 4; ++r)
        cohStoreU16(P1u + cb + (long)r * HH, f2b(acc[r]));
      asm volatile("s_waitcnt vmcnt(0)" ::: "memory");
      if (l == 0) cohStoreU16(gfx + wslot, (unsigned short)(t + 1));
    }
  } else {
    const unsigned short* myxpf = gfx + wslot;   // matching XP1 wave's flag
    for (int t = 0; t < Tt; ++t) {
      // xp1 dependency: single flag (same (j,wv) XP1 wave wrote exactly our
      // 16x16 tile); issue xb loads so their latency hides under gf1 poll.
      waitflag1(myxpf, (unsigned)(t + 1));
      const long cb = ((long)t * Bb + rowA + rb) * HH + ccol;
      float xb[4];
#pragma unroll
      for (int r = 0; r < 4; ++r)
        xb[r] = b2f(cohLoadU16(P1u + cb + (long)r * HH));
      f32x4 acc = {0, 0, 0, 0};
      if (t > 0) {
        waitflags(gf1, l, (unsigned)t);
        acc = kphase((const short*)P1 + (long)(t - 1) * (Bb * HH) + laneA, w, acc);
      }
#pragma unroll
      for (int r = 0; r < 4; ++r)
        cohStoreU16(P1u + cb + (long)r * HH, f2b(tanhf(acc[r] + xb[r])));
      asm volatile("s_waitcnt vmcnt(0)" ::: "memory");
      if (l == 0) cohStoreU16(gf1 + wslot, (unsigned short)(t + 1));
    }
  }
}

// fc: out[64][512] = h2_last @ Wfc^T + bfc (coherent A reads).
__global__ void fc_kernel(const __hip_bfloat16* __restrict__ A,
                          const __hip_bfloat16* __restrict__ W,
                          const float* __restrict__ bias,
                          float* __restrict__ C)
{
  const int l   = threadIdx.x;
  const int m0  = blockIdx.x << 4;
  const int n0  = blockIdx.y << 6;
  const int r16 = l & 15;
  const int lh  = l >> 4;

  const unsigned long long* Au =
      (const unsigned long long*)((const short*)A + (long)(m0 + r16) * HH);
  const short* Wp = (const short*)W;
  const long w0 = (long)(n0 + r16) * HH + (lh << 3);
  const long wS = (long)HH << 4;

  f32x4 acc0 = {0,0,0,0}, acc1 = {0,0,0,0}, acc2 = {0,0,0,0}, acc3 = {0,0,0,0};
  for (int kc = 0; kc < HH; kc += 32) {
    U16 a;
    a.u[0] = cohLoadU64(Au + (kc >> 2) + (lh << 1));
    a.u[1] = cohLoadU64(Au + (kc >> 2) + (lh << 1) + 1);
    bf16x8 b0 = *(const bf16x8*)(Wp + w0 +          kc);
    bf16x8 b1 = *(const bf16x8*)(Wp + w0 + wS     + kc);
    bf16x8 b2 = *(const bf16x8*)(Wp + w0 + 2 * wS + kc);
    bf16x8 b3 = *(const bf16x8*)(Wp + w0 + 3 * wS + kc);
    acc0 = __builtin_amdgcn_mfma_f32_16x16x32_bf16(a.v, b0, acc0, 0, 0, 0);
    acc1 = __builtin_amdgcn_mfma_f32_16x16x32_bf16(a.v, b1, acc1, 0, 0, 0);
    acc2 = __builtin_amdgcn_mfma_f32_16x16x32_bf16(a.v, b2, acc2, 0, 0, 0);
    acc3 = __builtin_amdgcn_mfma_f32_16x16x32_bf16(a.v, b3, acc3, 0, 0, 0);
  }
  const int col = l & 15;
  const int rbb = (l >> 4) << 2;
#define FCEP(FIDX, ACC)                                                       \
  { const int n = n0 + (FIDX << 4) + col;                                     \
    _Pragma("unroll")                                                         \
    for (int r = 0; r < 4; ++r)                                               \
      C[(long)(m0 + rbb + r) * OUTN + n] = ACC[r] + bias[n]; }
  FCEP(0, acc0) FCEP(1, acc1) FCEP(2, acc2) FCEP(3, acc3)
#undef FCEP
}

extern "C" void kernel_launch(void* const* d_in, const int* in_sizes, int n_in,
                              void* d_out, int out_size, void* d_ws, size_t ws_size,
                              hipStream_t stream)
{
  const float* x   = (const float*)d_in[0];
  const float* Wx0 = (const float*)d_in[1];
  const float* bx0 = (const float*)d_in[2];
  const float* Wh0 = (const float*)d_in[3];
  const float* bh0 = (const float*)d_in[4];
  const float* Wx1 = (const float*)d_in[5];
  const float* bx1 = (const float*)d_in[6];
  const float* Wh1 = (const float*)d_in[7];
  const float* bh1 = (const float*)d_in[8];
  const float* Wfc = (const float*)d_in[9];
  const float* bfc = (const float*)d_in[10];

  char* ws = (char*)d_ws;
  const long SZ_XBF = (long)Bb * Tt * INN * 2;
  const long SZ_P   = (long)Bb * Tt * HH  * 2;
  __hip_bfloat16* xbf   = (__hip_bfloat16*)(ws);
  __hip_bfloat16* P0    = (__hip_bfloat16*)(ws + SZ_XBF);          // h1 [T][B][H]
  __hip_bfloat16* P1    = (__hip_bfloat16*)(ws + SZ_XBF + SZ_P);   // xp1/h2 [T][B][H]
  __hip_bfloat16* Wx0b  = (__hip_bfloat16*)(ws + SZ_XBF + 2 * SZ_P);
  __hip_bfloat16* Wh0b  = (__hip_bfloat16*)((char*)Wx0b + (long)HH * INN * 2);
  __hip_bfloat16* Wx1b  = (__hip_bfloat16*)((char*)Wh0b + (long)HH * HH * 2);
  __hip_bfloat16* Wh1b  = (__hip_bfloat16*)((char*)Wx1b + (long)HH * HH * 2);
  __hip_bfloat16* Wfcb  = (__hip_bfloat16*)((char*)Wh1b + (long)HH * HH * 2);
  float*          b0sum = (float*)((char*)Wfcb + (long)OUTN * HH * 2);
  float*          b1sum = (float*)((char*)b0sum + HH * 4);
  unsigned short* flg   = (unsigned short*)((char*)b1sum + HH * 4);

  const int FLGN16 = 3 * NGRP * NSLOT;   // 768 u16 = 1536 B

  {
    int n4;
    n4 = (Bb * Tt * INN) / 4; cvt4<<<(n4 + 255) / 256, 256, 0, stream>>>(x,   (unsigned short*)xbf,  n4);
    n4 = (HH * INN) / 4;      cvt4<<<(n4 + 255) / 256, 256, 0, stream>>>(Wx0, (unsigned short*)Wx0b, n4);
    n4 = (HH * HH) / 4;       cvt4<<<(n4 + 255) / 256, 256, 0, stream>>>(Wh0, (unsigned short*)Wh0b, n4);
    n4 = (HH * HH) / 4;       cvt4<<<(n4 + 255) / 256, 256, 0, stream>>>(Wx1, (unsigned short*)Wx1b, n4);
    n4 = (HH * HH) / 4;       cvt4<<<(n4 + 255) / 256, 256, 0, stream>>>(Wh1, (unsigned short*)Wh1b, n4);
    n4 = (OUTN * HH) / 4;     cvt4<<<(n4 + 255) / 256, 256, 0, stream>>>(Wfc, (unsigned short*)Wfcb, n4);
    addv<<<4, 256, 0, stream>>>(bx0, bh0, b0sum, HH);
    addv<<<4, 256, 0, stream>>>(bx1, bh1, b1sum, HH);
    zerok<<<1, 256, 0, stream>>>((unsigned int*)flg, FLGN16 / 2);
  }

  rnn3<<<dim3(384), 128, 0, stream>>>(
      xbf, Wx0b, Wh0b, Wx1b, Wh1b, b0sum, b1sum, P0, P1, flg);

  fc_kernel<<<dim3(Bb / 16, OUTN / 64), 64, 0, stream>>>(
      P1 + (long)(Tt - 1) * Bb * HH, Wfcb, bfc, (float*)d_out);
}

// Round 15
// 3198.094 us; speedup vs baseline: 1.8970x; 1.8970x over previous
//
#include <hip/hip_runtime.h>
#include <hip/hip_bf16.h>

#define Bb   64
#define Tt   512
#define INN  256
#define HH   1024
#define OUTN 512

#define NCOL 32              // output cols per block
#define MG   16              // batch rows per group
#define NGRP (Bb / MG)       // 4 groups
#define NSLOT 64             // wave flags per (group, stage) = 32 blocks x 2 waves
#define FSTR 8               // flag stride in u32 (32 B) — R11 geometry (proven)

typedef __attribute__((ext_vector_type(8))) short bf16x8;
typedef __attribute__((ext_vector_type(4))) float f32x4;

__device__ __forceinline__ unsigned short f2b(float f) {
  unsigned u = __float_as_uint(f);
  u += 0x7FFFu + ((u >> 16) & 1u);
  return (unsigned short)(u >> 16);
}
__device__ __forceinline__ float b2f(unsigned short u) {
  return __uint_as_float((unsigned)u << 16);
}

__device__ __forceinline__ unsigned int cohLoadU32(const unsigned int* p) {
  return __hip_atomic_load(p, __ATOMIC_RELAXED, __HIP_MEMORY_SCOPE_AGENT);
}
__device__ __forceinline__ unsigned long long cohLoadU64(const unsigned long long* p) {
  return __hip_atomic_load(p, __ATOMIC_RELAXED, __HIP_MEMORY_SCOPE_AGENT);
}
__device__ __forceinline__ unsigned short cohLoadU16(const unsigned short* p) {
  return __hip_atomic_load(p, __ATOMIC_RELAXED, __HIP_MEMORY_SCOPE_AGENT);
}
__device__ __forceinline__ void cohStoreU16(unsigned short* p, unsigned short v) {
  __hip_atomic_store(p, v, __ATOMIC_RELAXED, __HIP_MEMORY_SCOPE_AGENT);
}
__device__ __forceinline__ void cohStoreU32(unsigned int* p, unsigned int v) {
  __hip_atomic_store(p, v, __ATOMIC_RELAXED, __HIP_MEMORY_SCOPE_AGENT);
}

__device__ __forceinline__ f32x4 splat4(float v) { f32x4 r = {v, v, v, v}; return r; }

union U16 { unsigned long long u[2]; bf16x8 v; };

// A-load: PLAIN CACHED (L1/L2-allocating) pipelined 16B load, literal byte
// offset. Safe because (a) each P[t] address is read only after its domain
// flag (producers' agent stores are at the MALL by then; L2 line was never
// touched earlier this launch — kernel-launch acquire invalidated it), and
// (b) every kphase-read address holds its FINAL deterministic value, so even
// a stale line across graph replays is bit-identical. The intermediate-value
// xb read (xp1, later overwritten) stays coherent below.
#define ALOADO(d, p, OFF)                                                     \
  asm volatile("global_load_dwordx4 %0, %1, off offset:" #OFF                 \
               : "=v"(d) : "v"(p))
#define VMW(N)                                                                \
  do {                                                                        \
    asm volatile("s_waitcnt vmcnt(" #N ")" ::: "memory");                     \
    __builtin_amdgcn_sched_barrier(0);                                        \
  } while (0)

// fp32 -> bf16 (RNE), vectorized x4
__global__ void cvt4(const float* __restrict__ in, unsigned short* __restrict__ out, int n4) {
  int i = blockIdx.x * blockDim.x + threadIdx.x;
  if (i >= n4) return;
  float4 v = ((const float4*)in)[i];
  ushort4 o;
  o.x = f2b(v.x); o.y = f2b(v.y); o.z = f2b(v.z); o.w = f2b(v.w);
  ((ushort4*)out)[i] = o;
}

__global__ void addv(const float* __restrict__ a, const float* __restrict__ b,
                     float* __restrict__ o, int n) {
  int i = blockIdx.x * blockDim.x + threadIdx.x;
  if (i < n) o[i] = a[i] + b[i];
}

__global__ void zerok(unsigned int* __restrict__ p, int n) {
  int i = blockIdx.x * blockDim.x + threadIdx.x;
  if (i < n) p[i] = 0u;
}

// Poll 64 per-wave flags (lane l watches slot l); sleep-backoff spin.
__device__ __forceinline__ void waitflags(const unsigned int* gf, int l, unsigned need) {
#pragma clang loop unroll(disable)
  for (int guard = 0; guard < 4000000; ++guard) {
    unsigned f = cohLoadU32(gf + l * FSTR);
    if (__all((int)(f >= need))) return;
    __builtin_amdgcn_s_sleep(1);
  }
}
// Poll a single flag slot (wave-uniform address).
__device__ __forceinline__ void waitflag1(const unsigned int* slot, unsigned need) {
#pragma clang loop unroll(disable)
  for (int guard = 0; guard < 4000000; ++guard) {
    if (cohLoadU32(slot) >= need) return;
    __builtin_amdgcn_s_sleep(1);
  }
}

// One K=1024 GEMM phase for this lane's 16x16 tile.
// A: 32 plain-cached b128 loads, ALL issued up-front, drained with counted
// vmcnt 24/16/8/0. W (B-operand): 32 bf16x8 resident in AGPRs (laundered
// "+a" at entry each call so values stay put; no remat, no LICM copies).
#define ISSUE8(V, O0, O1, O2, O3, O4, O5, O6, O7)                             \
  ALOADO(V##0, Ap, O0); ALOADO(V##1, Ap, O1); ALOADO(V##2, Ap, O2);           \
  ALOADO(V##3, Ap, O3); ALOADO(V##4, Ap, O4); ALOADO(V##5, Ap, O5);           \
  ALOADO(V##6, Ap, O6); ALOADO(V##7, Ap, O7);
#define COMP8(V, WI)                                                          \
  acc  = __builtin_amdgcn_mfma_f32_16x16x32_bf16(V##0, w[(WI)+0], acc,  0,0,0);\
  acc2 = __builtin_amdgcn_mfma_f32_16x16x32_bf16(V##1, w[(WI)+1], acc2, 0,0,0);\
  acc  = __builtin_amdgcn_mfma_f32_16x16x32_bf16(V##2, w[(WI)+2], acc,  0,0,0);\
  acc2 = __builtin_amdgcn_mfma_f32_16x16x32_bf16(V##3, w[(WI)+3], acc2, 0,0,0);\
  acc  = __builtin_amdgcn_mfma_f32_16x16x32_bf16(V##4, w[(WI)+4], acc,  0,0,0);\
  acc2 = __builtin_amdgcn_mfma_f32_16x16x32_bf16(V##5, w[(WI)+5], acc2, 0,0,0);\
  acc  = __builtin_amdgcn_mfma_f32_16x16x32_bf16(V##6, w[(WI)+6], acc,  0,0,0);\
  acc2 = __builtin_amdgcn_mfma_f32_16x16x32_bf16(V##7, w[(WI)+7], acc2, 0,0,0);

__device__ __forceinline__ f32x4 kphase(const short* Ap, bf16x8* w, f32x4 acc) {
#pragma unroll
  for (int c = 0; c < 32; ++c) asm volatile("" : "+a"(w[c]));   // pin in AGPRs
  f32x4 acc2 = {0, 0, 0, 0};
  bf16x8 A_0, A_1, A_2, A_3, A_4, A_5, A_6, A_7;
  bf16x8 B_0, B_1, B_2, B_3, B_4, B_5, B_6, B_7;
  bf16x8 C_0, C_1, C_2, C_3, C_4, C_5, C_6, C_7;
  bf16x8 D_0, D_1, D_2, D_3, D_4, D_5, D_6, D_7;
  ISSUE8(A_,    0,   64,  128,  192,  256,  320,  384,  448)
  ISSUE8(B_,  512,  576,  640,  704,  768,  832,  896,  960)
  ISSUE8(C_, 1024, 1088, 1152, 1216, 1280, 1344, 1408, 1472)
  ISSUE8(D_, 1536, 1600, 1664, 1728, 1792, 1856, 1920, 1984)
  VMW(24); COMP8(A_,  0)
  VMW(16); COMP8(B_,  8)
  VMW(8);  COMP8(C_, 16)
  VMW(0);  COMP8(D_, 24)
  return acc + acc2;
}

// 3-stage pipelined persistent RNN (R11 structure — proven 3.35 ms), 384
// blocks (stage = bid%3), 128 thr (2 waves), NO LDS; W in AGPRs (128/wave).
//  stage 0 (L0):  h1_t = tanh(Wh0 h1_{t-1} + Wx0 x_t + b0)      -> P0[t], gf0
//  stage 1 (XP1): xp1_t = Wx1 h1_t + b1                         -> P1[t], gfx
//  stage 2 (WH1): h2_t = tanh(Wh1 h2_{t-1} + xp1_t) (in-place)  -> P1[t], gf1
__global__ __launch_bounds__(128) void rnn3(
    const __hip_bfloat16* __restrict__ xs,                        // [B][T][IN]
    const __hip_bfloat16* __restrict__ Wx0, const __hip_bfloat16* __restrict__ Wh0,
    const __hip_bfloat16* __restrict__ Wx1, const __hip_bfloat16* __restrict__ Wh1,
    const float* __restrict__ b0s, const float* __restrict__ b1s,
    __hip_bfloat16* __restrict__ P0, __hip_bfloat16* __restrict__ P1,
    unsigned int* flags)
{
  const int tid = threadIdx.x;
  const int l   = tid & 63;
  const int wv  = tid >> 6;
  const int bid = blockIdx.x;
  const int stage = bid % 3;
  const int idx = bid / 3;          // 0..127
  const int j   = idx & 31;
  const int g   = idx >> 5;
  const int n0  = j * NCOL;
  const int rowA = g * MG;
  const int fr = l & 15;
  const int lh = l >> 4;
  const int rb = lh << 2;
  const int ccol = n0 + wv * 16 + fr;

  unsigned int* gf0 = flags + (0 * NGRP + g) * (NSLOT * FSTR);
  unsigned int* gfx = flags + (1 * NGRP + g) * (NSLOT * FSTR);
  unsigned int* gf1 = flags + (2 * NGRP + g) * (NSLOT * FSTR);
  const int wslot = (j * 2 + wv) * FSTR;
  const long laneA = (long)(rowA + fr) * HH + (lh << 3);
  unsigned short* P0u = (unsigned short*)P0;
  unsigned short* P1u = (unsigned short*)P1;

  // This wave's 16-col W slice -> AGPRs (32 x bf16x8 = 128 AGPRs).
  const short* Wg = (const short*)(stage == 0 ? Wh0 : (stage == 1 ? Wx1 : Wh1));
  const short* Wgrow = Wg + (long)ccol * HH + (lh << 3);
  bf16x8 w[32];
#pragma unroll
  for (int c = 0; c < 32; ++c) w[c] = *(const bf16x8*)(Wgrow + (c << 5));
#pragma unroll
  for (int c = 0; c < 32; ++c) asm volatile("" : "+a"(w[c]));

  if (stage == 0) {
    const float bias = b0s[ccol];
    const short* xrow = (const short*)xs + (long)(rowA + fr) * (Tt * INN) + (lh << 3);
    const short* Wx0row = (const short*)Wx0 + (long)ccol * INN + (lh << 3);
    bf16x8 wx[8];
#pragma unroll
    for (int c = 0; c < 8; ++c) wx[c] = *(const bf16x8*)(Wx0row + (c << 5));
#pragma unroll
    for (int c = 0; c < 8; ++c) asm volatile("" : "+a"(wx[c]));
    f32x4 acc = splat4(bias);
#pragma unroll
    for (int c = 0; c < 8; ++c) {     // xp0 for t=0
      bf16x8 a = *(const bf16x8*)(xrow + (c << 5));
      acc = __builtin_amdgcn_mfma_f32_16x16x32_bf16(a, wx[c], acc, 0, 0, 0);
    }
    for (int t = 0; t < Tt; ++t) {
      if (t > 0) {
        waitflags(gf0, l, (unsigned)t);
        acc = kphase((const short*)P0 + (long)(t - 1) * (Bb * HH) + laneA, w, acc);
      }
      const long cb = ((long)t * Bb + rowA + rb) * HH + ccol;
#pragma unroll
      for (int r = 0; r < 4; ++r)
        cohStoreU16(P0u + cb + (long)r * HH, f2b(tanhf(acc[r])));
      asm volatile("s_waitcnt vmcnt(0)" ::: "memory");
      if (l == 0) cohStoreU32(gf0 + wslot, (unsigned)(t + 1));
      if (t + 1 < Tt) {               // xp0 for t+1, in the straggler window
        acc = splat4(bias);
        const short* xr = xrow + (t + 1) * INN;
#pragma unroll
        for (int c = 0; c < 8; ++c) {
          bf16x8 a = *(const bf16x8*)(xr + (c << 5));
          acc = __builtin_amdgcn_mfma_f32_16x16x32_bf16(a, wx[c], acc, 0, 0, 0);
        }
      }
    }
  } else if (stage == 1) {
    const float bias = b1s[ccol];
    for (int t = 0; t < Tt; ++t) {
      waitflags(gf0, l, (unsigned)(t + 1));
      f32x4 acc = kphase((const short*)P0 + (long)t * (Bb * HH) + laneA, w,
                         splat4(bias));
      const long cb = ((long)t * Bb + rowA + rb) * HH + ccol;
#pragma unroll
      for (int r = 0; r < 4; ++r)
        cohStoreU16(P1u + cb + (long)r * HH, f2b(acc[r]));
      asm volatile("s_waitcnt vmcnt(0)" ::: "memory");
      if (l == 0) cohStoreU32(gfx + wslot, (unsigned)(t + 1));
    }
  } else {
    const unsigned int* myxpf = gfx + wslot;   // matching XP1 wave's flag
    for (int t = 0; t < Tt; ++t) {
      // xp1 dependency: single flag (same (j,wv) XP1 wave wrote exactly our
      // 16x16 tile). xb reads an INTERMEDIATE value (xp1, later overwritten
      // by h2) -> must stay COHERENT (stale-L2 across replays would be h2).
      waitflag1(myxpf, (unsigned)(t + 1));
      const long cb = ((long)t * Bb + rowA + rb) * HH + ccol;
      float xb[4];
#pragma unroll
      for (int r = 0; r < 4; ++r)
        xb[r] = b2f(cohLoadU16(P1u + cb + (long)r * HH));
      f32x4 acc = {0, 0, 0, 0};
      if (t > 0) {
        waitflags(gf1, l, (unsigned)t);
        acc = kphase((const short*)P1 + (long)(t - 1) * (Bb * HH) + laneA, w, acc);
      }
#pragma unroll
      for (int r = 0; r < 4; ++r)
        cohStoreU16(P1u + cb + (long)r * HH, f2b(tanhf(acc[r] + xb[r])));
      asm volatile("s_waitcnt vmcnt(0)" ::: "memory");
      if (l == 0) cohStoreU32(gf1 + wslot, (unsigned)(t + 1));
    }
  }
}

// fc: out[64][512] = h2_last @ Wfc^T + bfc (coherent A reads — h2_last is
// final-valued, but coherent keeps it simple; fc is off the critical path).
__global__ void fc_kernel(const __hip_bfloat16* __restrict__ A,
                          const __hip_bfloat16* __restrict__ W,
                          const float* __restrict__ bias,
                          float* __restrict__ C)
{
  const int l   = threadIdx.x;
  const int m0  = blockIdx.x << 4;
  const int n0  = blockIdx.y << 6;
  const int r16 = l & 15;
  const int lh  = l >> 4;

  const unsigned long long* Au =
      (const unsigned long long*)((const short*)A + (long)(m0 + r16) * HH);
  const short* Wp = (const short*)W;
  const long w0 = (long)(n0 + r16) * HH + (lh << 3);
  const long wS = (long)HH << 4;

  f32x4 acc0 = {0,0,0,0}, acc1 = {0,0,0,0}, acc2 = {0,0,0,0}, acc3 = {0,0,0,0};
  for (int kc = 0; kc < HH; kc += 32) {
    U16 a;
    a.u[0] = cohLoadU64(Au + (kc >> 2) + (lh << 1));
    a.u[1] = cohLoadU64(Au + (kc >> 2) + (lh << 1) + 1);
    bf16x8 b0 = *(const bf16x8*)(Wp + w0 +          kc);
    bf16x8 b1 = *(const bf16x8*)(Wp + w0 + wS     + kc);
    bf16x8 b2 = *(const bf16x8*)(Wp + w0 + 2 * wS + kc);
    bf16x8 b3 = *(const bf16x8*)(Wp + w0 + 3 * wS + kc);
    acc0 = __builtin_amdgcn_mfma_f32_16x16x32_bf16(a.v, b0, acc0, 0, 0, 0);
    acc1 = __builtin_amdgcn_mfma_f32_16x16x32_bf16(a.v, b1, acc1, 0, 0, 0);
    acc2 = __builtin_amdgcn_mfma_f32_16x16x32_bf16(a.v, b2, acc2, 0, 0, 0);
    acc3 = __builtin_amdgcn_mfma_f32_16x16x32_bf16(a.v, b3, acc3, 0, 0, 0);
  }
  const int col = l & 15;
  const int rbb = (l >> 4) << 2;
#define FCEP(FIDX, ACC)                                                       \
  { const int n = n0 + (FIDX << 4) + col;                                     \
    _Pragma("unroll")                                                         \
    for (int r = 0; r < 4; ++r)                                               \
      C[(long)(m0 + rbb + r) * OUTN + n] = ACC[r] + bias[n]; }
  FCEP(0, acc0) FCEP(1, acc1) FCEP(2, acc2) FCEP(3, acc3)
#undef FCEP
}

extern "C" void kernel_launch(void* const* d_in, const int* in_sizes, int n_in,
                              void* d_out, int out_size, void* d_ws, size_t ws_size,
                              hipStream_t stream)
{
  const float* x   = (const float*)d_in[0];
  const float* Wx0 = (const float*)d_in[1];
  const float* bx0 = (const float*)d_in[2];
  const float* Wh0 = (const float*)d_in[3];
  const float* bh0 = (const float*)d_in[4];
  const float* Wx1 = (const float*)d_in[5];
  const float* bx1 = (const float*)d_in[6];
  const float* Wh1 = (const float*)d_in[7];
  const float* bh1 = (const float*)d_in[8];
  const float* Wfc = (const float*)d_in[9];
  const float* bfc = (const float*)d_in[10];

  char* ws = (char*)d_ws;
  const long SZ_XBF = (long)Bb * Tt * INN * 2;
  const long SZ_P   = (long)Bb * Tt * HH  * 2;
  __hip_bfloat16* xbf   = (__hip_bfloat16*)(ws);
  __hip_bfloat16* P0    = (__hip_bfloat16*)(ws + SZ_XBF);          // h1 [T][B][H]
  __hip_bfloat16* P1    = (__hip_bfloat16*)(ws + SZ_XBF + SZ_P);   // xp1/h2 [T][B][H]
  __hip_bfloat16* Wx0b  = (__hip_bfloat16*)(ws + SZ_XBF + 2 * SZ_P);
  __hip_bfloat16* Wh0b  = (__hip_bfloat16*)((char*)Wx0b + (long)HH * INN * 2);
  __hip_bfloat16* Wx1b  = (__hip_bfloat16*)((char*)Wh0b + (long)HH * HH * 2);
  __hip_bfloat16* Wh1b  = (__hip_bfloat16*)((char*)Wx1b + (long)HH * HH * 2);
  __hip_bfloat16* Wfcb  = (__hip_bfloat16*)((char*)Wh1b + (long)HH * HH * 2);
  float*          b0sum = (float*)((char*)Wfcb + (long)OUTN * HH * 2);
  float*          b1sum = (float*)((char*)b0sum + HH * 4);
  unsigned int*   flg   = (unsigned int*)((char*)b1sum + HH * 4);

  const int FLGN = 3 * NGRP * NSLOT * FSTR;   // 6144 u32

  {
    int n4;
    n4 = (Bb * Tt * INN) / 4; cvt4<<<(n4 + 255) / 256, 256, 0, stream>>>(x,   (unsigned short*)xbf,  n4);
    n4 = (HH * INN) / 4;      cvt4<<<(n4 + 255) / 256, 256, 0, stream>>>(Wx0, (unsigned short*)Wx0b, n4);
    n4 = (HH * HH) / 4;       cvt4<<<(n4 + 255) / 256, 256, 0, stream>>>(Wh0, (unsigned short*)Wh0b, n4);
    n4 = (HH * HH) / 4;       cvt4<<<(n4 + 255) / 256, 256, 0, stream>>>(Wx1, (unsigned short*)Wx1b, n4);
    n4 = (HH * HH) / 4;       cvt4<<<(n4 + 255) / 256, 256, 0, stream>>>(Wh1, (unsigned short*)Wh1b, n4);
    n4 = (OUTN * HH) / 4;     cvt4<<<(n4 + 255) / 256, 256, 0, stream>>>(Wfc, (unsigned short*)Wfcb, n4);
    addv<<<4, 256, 0, stream>>>(bx0, bh0, b0sum, HH);
    addv<<<4, 256, 0, stream>>>(bx1, bh1, b1sum, HH);
    zerok<<<(FLGN + 255) / 256, 256, 0, stream>>>(flg, FLGN);
  }

  rnn3<<<dim3(384), 128, 0, stream>>>(
      xbf, Wx0b, Wh0b, Wx1b, Wh1b, b0sum, b1sum, P0, P1, flg);

  fc_kernel<<<dim3(Bb / 16, OUTN / 64), 64, 0, stream>>>(
      P1 + (long)(Tt - 1) * Bb * HH, Wfcb, bfc, (float*)d_out);
}